// Round 17
// baseline (8827.294 us; speedup 1.0000x reference)
//
#include <hip/hip_runtime.h>
#include <hip/hip_fp16.h>

typedef _Float16 f16x8 __attribute__((ext_vector_type(8)));
typedef float f32x4 __attribute__((ext_vector_type(4)));
typedef float f32x16 __attribute__((ext_vector_type(16)));
typedef unsigned short u16;
typedef unsigned int u32;

#define T_STEPS 512
#define BATCH   512
#define DTF     0.01f

// workspace layout (bytes)
#define CTR_OFF 0
#define CTR_SZ  1048576                     // slot counters + per-(g,slot) flags
#define WB_OFF  (CTR_OFF + CTR_SZ)
#define WB_SZ   (32*200*384*2)              // 4,915,200  [slice][mat*100+unit][384 u16] 32x32 B-frags
#define WRB_OFF (WB_OFF + WB_SZ)
#define WRB_SZ  (4*24*64*8*2)               // 98,304     W_r f16 B-frag layout (16x16x32)
#define ST_OFF  (WRB_OFF + WRB_SZ)
#define ST_SZ   (2*8*64*1536*2)             // 3,145,728  state [buf][g][row 64][k' 1536] f16
#define WS_NEED (ST_OFF + ST_SZ)

#define MFMA32(a,b,c) __builtin_amdgcn_mfma_f32_32x32x16_f16((a),(b),(c),0,0,0)
#define MFMA16(a,b,c) __builtin_amdgcn_mfma_f32_16x16x32_f16((a),(b),(c),0,0,0)

// Intra-XCD acquire: L2 is the coherence point, L1 write-through => L1-only
// invalidate; one wave per CU. [Verified rounds 3-16.]
#define ACQUIRE_L1() asm volatile("s_waitcnt vmcnt(0)\n\tbuffer_inv sc0" ::: "memory")

__device__ __forceinline__ u16 f2h(float f){ _Float16 h = (_Float16)f; return *reinterpret_cast<u16*>(&h); }

__device__ __forceinline__ float ftanh(float x){
  float a = fminf(fmaxf(x, -12.f), 12.f);
  float e = __expf(2.f * a);
  return 1.f - 2.f * __builtin_amdgcn_rcpf(e + 1.f);
}

// ---- 32x32x16 fragment maps [verified r12/r14: absmax 0.03125] ----
// A (32x16): lane holds A[l&31][(l>>5)*8 + e]
// B (16x32): lane holds B[(l>>5)*8 + e][l&31]
// C (32x32): lane covers col = l&31, rows = (e&3) + 8*(e>>2) + 4*(l>>5)
// Wb layout unchanged (prep identical to r12-16).

__global__ __launch_bounds__(64) void prep_weights(const float* __restrict__ Wh,
                                                   const float* __restrict__ Wp,
                                                   const float* __restrict__ Wr,
                                                   u16* __restrict__ Wb, u16* __restrict__ Wrb){
  int b = blockIdx.x, l = threadIdx.x;
  if (b < 6400){
    int s = b / 200, r2 = b % 200;
    int m2 = r2 / 100, u = r2 % 100;
    if (l < 48){
      int c = l >> 1, kh = l & 1;
      int gg = c*2 + kh, rr = gg >> 3, cc = gg & 7;
      size_t dst = (size_t)s*76800 + (size_t)(m2*100 + u)*384 + (size_t)rr*64 + (size_t)((cc ^ (rr & 7))*8);
      const float* W = m2 ? Wp : Wh;
      const float* src = W + (size_t)(s*24 + c)*1600 + u*16 + kh*8;
      f16x8 o;
#pragma unroll
      for (int e = 0; e < 8; ++e) o[e] = (_Float16)src[e];
      *reinterpret_cast<f16x8*>(Wb + dst) = o;
    }
  } else {
    int b2 = b - 6400;                      // 0..95  (W_r, 16x16x32 B-frags)
    int nt = b2 / 24, kt = b2 % 24;
    int c = nt*16 + (l & 15), k = kt*32 + (l >> 4)*8;
    const float* src = Wr + (size_t)c*768 + k;
    f16x8 o;
#pragma unroll
    for (int e = 0; e < 8; ++e) o[e] = (_Float16)src[e];
    *reinterpret_cast<f16x8*>(Wrb + ((size_t)b2*64 + l)*8) = o;
  }
}

// grid = 256 x 512 threads (8 waves). Group = PHYSICAL XCD, slot via atomicAdd.
// Wave wv: q = wv>>1 (K-quarter, 25 units), mat = wv&1 (0=W_h, 1=W_p).
// Each wave: 25 B-frags in VGPR (100 regs — resident, unlike r16's 200),
// computes BOTH m-tiles. 2 waves/SIMD => TLP hides A-load latency. LDS weight
// reads: 0. Reduce via 16-region e-major scratch (conflict-free, r14).
// Updaters w0(m0)/w1(m1) hold fp32 state. Sync = r15 per-slot flags.
__global__ __launch_bounds__(512, 1) void rnn_main(
    const float* __restrict__ x, const float* __restrict__ bh_g, const float* __restrict__ bp_g,
    const float* __restrict__ br_g, const u16* __restrict__ Wb, const u16* __restrict__ Wrb,
    u16* __restrict__ st, u32* __restrict__ ctr, float* __restrict__ out)
{
  extern __shared__ u16 smem[];             // 90,112 requested (forces 1 block/CU); 64KB used
  __shared__ int s_dead, s_slot, s_xcd;
  float* scr = reinterpret_cast<float*>(smem);

  const int tid = threadIdx.x;
  if (tid == 0){
    s_dead = 0;
    u32 xcd;
    asm volatile("s_getreg_b32 %0, hwreg(HW_REG_XCC_ID)" : "=s"(xcd));
    xcd &= 7u;
    s_xcd  = (int)xcd;
    s_slot = (int)atomicAdd(ctr + xcd, 1u); // device-scope, ctr pre-zeroed
  }
  __syncthreads();
  const int gx = s_xcd;
  const int s  = s_slot;
  if (s >= 32) return;

  const int c0   = s * 24;
  const int l    = tid & 63;
  const int wv   = tid >> 6;                // 0..7
  const int q    = wv >> 1;                 // K-quarter: units q*25..q*25+24
  const int matP = wv & 1;                  // 0=W_h, 1=W_p
  const int colW = l & 31;
  const int khB  = l >> 5;
  const bool validC = (colW < 24);
  const int colB = validC ? colW : colW - 24;
  const int gran = colB*2 + khB;
  const int grr  = gran >> 3, gcc = gran & 7;
  const int bfi  = grr*8 + (gcc ^ (grr & 7));   // f16x8 index within a 384-u16 unit-block

  // per-(g,slot) monotonic flags: FL[s*32], 128B stride  [r15]
  u32* FL = ctr + 2048 + (size_t)gx*16384;

  // B-fragments -> VGPRs (once): 25 units of this wave's (mat, quarter)
  f16x8 Bv[25];
  {
    const f16x8* WBg = reinterpret_cast<const f16x8*>(Wb);
    const size_t base = (size_t)s*9600 + (size_t)((matP ? 100 : 0) + q*25)*48 + bfi;
#pragma unroll
    for (int j = 0; j < 25; ++j) Bv[j] = WBg[base + (size_t)j*48];
  }

  const int dcol = c0 + (validC ? colW : 0);
  float bhv = 0.f, bpv = 0.f;
  if (wv < 2){ bhv = bh_g[dcol]; bpv = bp_g[dcol]; }

  float hz[16] = {}, hy[16] = {};           // fp32 master state (w0: m0, w1: m1)

  auto wait_flags = [&](u32 tgt){
    if (s_dead) return;
    long spins = 0;
    for (;;){
      bool ok = true;
      if (l < 32) ok = (__hip_atomic_load(FL + l*32, __ATOMIC_RELAXED, __HIP_MEMORY_SCOPE_AGENT) >= tgt);
      if (__all(ok)) break;
      __builtin_amdgcn_s_sleep(1);
      if (++spins > 1000000L){ if (l == 0) s_dead = 1; break; }
    }
  };

// reduce-scratch region base (floats): (m, mat, q) block of 16e x 64l
#define RG(mI,matI,qI) ((((mI)*2 + (matI))*4 + (qI))*1024)

// state loop: NU units, A tile-offset OFF0+i, B from VGPR Bv[BOFF+i] (static),
// both m-tiles, 4-deep A ring, optional square.
#define SLOOP(OFF0c, NUc, BOFFc, DOSQc) do { \
    f16x8 av0[4], av1[4]; \
    _Pragma("unroll") \
    for (int j = 0; j < 4; ++j){ \
      av0[j] = *reinterpret_cast<const f16x8*>(stb0 + (size_t)((OFF0c)+j)*16); \
      av1[j] = *reinterpret_cast<const f16x8*>(stb1 + (size_t)((OFF0c)+j)*16); \
    } \
    _Pragma("unroll") \
    for (int i = 0; i < (NUc); ++i){ \
      f16x8 a0 = av0[i&3], a1 = av1[i&3]; \
      if (i + 4 < (NUc)){ \
        av0[i&3] = *reinterpret_cast<const f16x8*>(stb0 + (size_t)((OFF0c)+i+4)*16); \
        av1[i&3] = *reinterpret_cast<const f16x8*>(stb1 + (size_t)((OFF0c)+i+4)*16); \
      } \
      if (DOSQc){ a0 = a0*a0; a1 = a1*a1; } \
      acc0 = MFMA32(a0, Bv[(BOFFc)+i], acc0); \
      acc1 = MFMA32(a1, Bv[(BOFFc)+i], acc1); \
    } } while (0)

#pragma unroll 1
  for (int t = 0; t < T_STEPS; ++t){
    // x prefetch + convert (quarter-0 waves only; both m; mat-flavored) — pre-wait
    f16x8 xa0[4], xa1[4];
    if (q == 0){
#pragma unroll
      for (int mm = 0; mm < 2; ++mm){
        const float* xb = x + ((size_t)t*BATCH + gx*64 + mm*32 + colW)*64 + khB*8;
#pragma unroll
        for (int u = 0; u < 4; ++u){
          const float4 uu = *reinterpret_cast<const float4*>(xb + u*16);
          const float4 vv = *reinterpret_cast<const float4*>(xb + u*16 + 4);
          f16x8 r;
          if (!matP){
            r[0]=(_Float16)uu.x; r[1]=(_Float16)uu.y; r[2]=(_Float16)uu.z; r[3]=(_Float16)uu.w;
            r[4]=(_Float16)vv.x; r[5]=(_Float16)vv.y; r[6]=(_Float16)vv.z; r[7]=(_Float16)vv.w;
          } else {
            r[0]=(_Float16)(uu.x*uu.x); r[1]=(_Float16)(uu.y*uu.y); r[2]=(_Float16)(uu.z*uu.z); r[3]=(_Float16)(uu.w*uu.w);
            r[4]=(_Float16)(vv.x*vv.x); r[5]=(_Float16)(vv.y*vv.y); r[6]=(_Float16)(vv.z*vv.z); r[7]=(_Float16)(vv.w*vv.w);
          }
          if (mm) xa1[u] = r; else xa0[u] = r;
        }
      }
    }

    if (wv == 0){
      if (t > 0) wait_flags((u32)t);        // all slots finished step t-1
      ACQUIRE_L1();                         // one L1 inv per CU (barrier orders it)
    }
    __syncthreads();
    if (s_dead) break;

    const u16* stb0 = st + ((((size_t)(t&1)*8 + gx)*64) + colW)*1536 + khB*8;
    const u16* stb1 = stb0 + (size_t)32*1536;

    f32x16 acc0 = {}, acc1 = {};
    if (q == 0){
#pragma unroll
      for (int u = 0; u < 4; ++u){          // x units 0..3 (pre-flavored)
        acc0 = MFMA32(xa0[u], Bv[u], acc0);
        acc1 = MFMA32(xa1[u], Bv[u], acc1);
      }
      if (!matP) SLOOP(0, 21, 4, 0); else SLOOP(0, 21, 4, 1);
    } else {
      const int off0 = q*25 - 4;            // tile k'-unit offset for first unit
      if (!matP) SLOOP(off0, 25, 0, 0); else SLOOP(off0, 25, 0, 1);
    }

    // partial exchange (e-major, conflict-free): updaters keep own partial
    if (wv == 0){
#pragma unroll
      for (int e = 0; e < 16; ++e) scr[RG(1,0,0) + e*64 + l] = acc1[e];
    } else if (wv == 1){
#pragma unroll
      for (int e = 0; e < 16; ++e) scr[RG(0,1,0) + e*64 + l] = acc0[e];
    } else {
#pragma unroll
      for (int e = 0; e < 16; ++e){
        scr[RG(0,matP,q) + e*64 + l] = acc0[e];
        scr[RG(1,matP,q) + e*64 + l] = acc1[e];
      }
    }
    __syncthreads();

    if (wv < 2){
      u16* wtb = st + (((size_t)((t+1)&1)*8 + gx)*64)*1536;
      const int mrow = wv*32;
#pragma unroll
      for (int e = 0; e < 16; ++e){
        float aH, aP;
        if (wv == 0){
          aH = acc0[e] + scr[RG(0,0,1)+e*64+l] + scr[RG(0,0,2)+e*64+l] + scr[RG(0,0,3)+e*64+l];
          aP = scr[RG(0,1,0)+e*64+l] + scr[RG(0,1,1)+e*64+l] + scr[RG(0,1,2)+e*64+l] + scr[RG(0,1,3)+e*64+l];
        } else {
          aP = acc1[e] + scr[RG(1,1,1)+e*64+l] + scr[RG(1,1,2)+e*64+l] + scr[RG(1,1,3)+e*64+l];
          aH = scr[RG(1,0,0)+e*64+l] + scr[RG(1,0,1)+e*64+l] + scr[RG(1,0,2)+e*64+l] + scr[RG(1,0,3)+e*64+l];
        }
        float hv = ftanh(aH + bhv);
        float pv = ftanh(aP + bpv);
        hz[e] += DTF * (hv + pv);
        hy[e] += DTF * hz[e];
        if (validC){
          int row = mrow + (e & 3) + 8*(e >> 2) + 4*khB;
          wtb[(size_t)row*1536 + dcol]       = f2h(hz[e]);
          wtb[(size_t)row*1536 + 768 + dcol] = f2h(hy[e]);
        }
      }
      asm volatile("s_waitcnt vmcnt(0)" ::: "memory");   // updater stores in XCD L2
    }
    __syncthreads();
    if (tid == 0)
      __hip_atomic_store(FL + s*32, (u32)(t+1), __ATOMIC_RELAXED, __HIP_MEMORY_SCOPE_AGENT);
  }
#undef SLOOP
#undef RG

  // final projection: out = hy @ W_r^T + b_r, slot-0 block (16x16x32 path)
  if (s == 0 && !s_dead){
    if (wv == 0){ wait_flags((u32)T_STEPS); ACQUIRE_L1(); }
    __syncthreads();
    if (!s_dead && wv < 4){
      const int colL = l & 15, kq4 = l >> 4;
      const u16* hyb = st + (((size_t)gx*64) + wv*16 + colL)*1536 + 768 + kq4*8;  // buf0
      const f16x8* Wr8 = reinterpret_cast<const f16x8*>(Wrb);
      f32x4 oc[4] = {};
#pragma unroll
      for (int kt = 0; kt < 24; ++kt){
        f16x8 a = *reinterpret_cast<const f16x8*>(hyb + (size_t)kt*32);
#pragma unroll
        for (int nt = 0; nt < 4; ++nt)
          oc[nt] = MFMA16(a, Wr8[(nt*24 + kt)*64 + l], oc[nt]);
      }
      const int rowC = wv*16 + kq4*4;
#pragma unroll
      for (int nt = 0; nt < 4; ++nt){
        float bb = br_g[nt*16 + colL];
#pragma unroll
        for (int e = 0; e < 4; ++e)
          out[(size_t)(gx*64 + rowC + e)*64 + nt*16 + colL] = oc[nt][e] + bb;
      }
    }
  }
}

extern "C" void kernel_launch(void* const* d_in, const int* in_sizes, int n_in,
                              void* d_out, int out_size, void* d_ws, size_t ws_size,
                              hipStream_t stream) {
  const float* x  = (const float*)d_in[0];
  const float* Wh = (const float*)d_in[1];
  const float* bh = (const float*)d_in[2];
  const float* Wp = (const float*)d_in[3];
  const float* bp = (const float*)d_in[4];
  const float* Wr = (const float*)d_in[5];
  const float* br = (const float*)d_in[6];
  float* out = (float*)d_out;

  if (ws_size < (size_t)WS_NEED) return;    // loud failure: output stays zero
  char* ws = (char*)d_ws;

  u16* Wb  = (u16*)(ws + WB_OFF);
  u16* Wrb = (u16*)(ws + WRB_OFF);
  u16* st  = (u16*)(ws + ST_OFF);
  u32* ctr = (u32*)(ws + CTR_OFF);

  hipMemsetAsync(ws + CTR_OFF, 0, CTR_SZ, stream);   // slot counters + flags
  hipMemsetAsync(ws + ST_OFF,  0, ST_SZ,  stream);   // zero initial state (t=0)

  prep_weights<<<6496, 64, 0, stream>>>(Wh, Wp, Wr, Wb, Wrb);

  (void)hipFuncSetAttribute(reinterpret_cast<const void*>(rnn_main),
                            hipFuncAttributeMaxDynamicSharedMemorySize, 90112);
  rnn_main<<<256, 512, 90112, stream>>>(x, bh, bp, br, Wb, Wrb, st, ctr, out);
}

// Round 18
// 7767.747 us; speedup vs baseline: 1.1364x; 1.1364x over previous
//
#include <hip/hip_runtime.h>
#include <hip/hip_fp16.h>

typedef _Float16 f16x8 __attribute__((ext_vector_type(8)));
typedef float f32x4 __attribute__((ext_vector_type(4)));
typedef float f32x16 __attribute__((ext_vector_type(16)));
typedef unsigned short u16;
typedef unsigned int u32;

#define T_STEPS 512
#define BATCH   512
#define DTF     0.01f

// workspace layout (bytes)
#define CTR_OFF 0
#define CTR_SZ  1048576                     // slot counters + per-(g,slot) flags
#define WB_OFF  (CTR_OFF + CTR_SZ)
#define WB_SZ   (32*200*384*2)              // 4,915,200  [slice][mat*100+unit][384 u16] 32x32 B-frags
#define WRB_OFF (WB_OFF + WB_SZ)
#define WRB_SZ  (4*24*64*8*2)               // 98,304     W_r f16 B-frag layout (16x16x32)
#define ST_OFF  (WRB_OFF + WRB_SZ)
#define ST_SZ   (2*8*64*1536*2)             // 3,145,728  state [buf][g][row 64][k' 1536] f16
#define WS_NEED (ST_OFF + ST_SZ)

#define MFMA32(a,b,c) __builtin_amdgcn_mfma_f32_32x32x16_f16((a),(b),(c),0,0,0)
#define MFMA16(a,b,c) __builtin_amdgcn_mfma_f32_16x16x32_f16((a),(b),(c),0,0,0)

// Intra-XCD acquire: L2 is the coherence point, L1 write-through => L1-only
// invalidate; one wave per CU. [Verified rounds 3-17.]
#define ACQUIRE_L1() asm volatile("s_waitcnt vmcnt(0)\n\tbuffer_inv sc0" ::: "memory")

__device__ __forceinline__ u16 f2h(float f){ _Float16 h = (_Float16)f; return *reinterpret_cast<u16*>(&h); }

__device__ __forceinline__ float ftanh(float x){
  float a = fminf(fmaxf(x, -12.f), 12.f);
  float e = __expf(2.f * a);
  return 1.f - 2.f * __builtin_amdgcn_rcpf(e + 1.f);
}

// ---- 32x32x16 fragment maps [verified r12/r14: absmax 0.03125] ----
// A (32x16): lane holds A[l&31][(l>>5)*8 + e]
// B (16x32): lane holds B[(l>>5)*8 + e][l&31]
// C (32x32): lane covers col = l&31, rows = (e&3) + 8*(e>>2) + 4*(l>>5)
// Wb layout unchanged (prep identical to r12-17).

__global__ __launch_bounds__(64) void prep_weights(const float* __restrict__ Wh,
                                                   const float* __restrict__ Wp,
                                                   const float* __restrict__ Wr,
                                                   u16* __restrict__ Wb, u16* __restrict__ Wrb){
  int b = blockIdx.x, l = threadIdx.x;
  if (b < 6400){
    int s = b / 200, r2 = b % 200;
    int m2 = r2 / 100, u = r2 % 100;
    if (l < 48){
      int c = l >> 1, kh = l & 1;
      int gg = c*2 + kh, rr = gg >> 3, cc = gg & 7;
      size_t dst = (size_t)s*76800 + (size_t)(m2*100 + u)*384 + (size_t)rr*64 + (size_t)((cc ^ (rr & 7))*8);
      const float* W = m2 ? Wp : Wh;
      const float* src = W + (size_t)(s*24 + c)*1600 + u*16 + kh*8;
      f16x8 o;
#pragma unroll
      for (int e = 0; e < 8; ++e) o[e] = (_Float16)src[e];
      *reinterpret_cast<f16x8*>(Wb + dst) = o;
    }
  } else {
    int b2 = b - 6400;                      // 0..95  (W_r, 16x16x32 B-frags)
    int nt = b2 / 24, kt = b2 % 24;
    int c = nt*16 + (l & 15), k = kt*32 + (l >> 4)*8;
    const float* src = Wr + (size_t)c*768 + k;
    f16x8 o;
#pragma unroll
    for (int e = 0; e < 8; ++e) o[e] = (_Float16)src[e];
    *reinterpret_cast<f16x8*>(Wrb + ((size_t)b2*64 + l)*8) = o;
  }
}

// grid = 256 x 256 (4 waves). Group = PHYSICAL XCD, slot via atomicAdd.
// Slot s owns out-cols [s*24,+24) of BOTH W_h/W_p. THIS ROUND: wave = (mat,
// K-half), computing BOTH m-tiles from ONE LDS B-read (read-once-use-twice):
// ds_read_b128 per block per step 400 -> 200 (the r12-validated lever),
// with B kept in LDS (no VGPR-residency gamble — r16/r17 both spilled).
// A-loads double (global, 8-deep dual ring, overlappable). Exchange via the
// r14-proven 8KB e-major scratch in 3 phases; updaters w0(m0)/w1(m1) hold
// fp32 state. Sync = r15 per-slot flags.
__global__ __launch_bounds__(256, 1) void rnn_main(
    const float* __restrict__ x, const float* __restrict__ bh_g, const float* __restrict__ bp_g,
    const float* __restrict__ br_g, const u16* __restrict__ Wb, const u16* __restrict__ Wrb,
    u16* __restrict__ st, u32* __restrict__ ctr, float* __restrict__ out)
{
  extern __shared__ u16 smem[];             // [0,153600): B-frags; [153600,161792): scratch
  __shared__ int s_dead, s_slot, s_xcd;

  const int tid = threadIdx.x;
  if (tid == 0){
    s_dead = 0;
    u32 xcd;
    asm volatile("s_getreg_b32 %0, hwreg(HW_REG_XCC_ID)" : "=s"(xcd));
    xcd &= 7u;
    s_xcd  = (int)xcd;
    s_slot = (int)atomicAdd(ctr + xcd, 1u); // device-scope, ctr pre-zeroed
  }
  __syncthreads();
  const int gx = s_xcd;
  const int s  = s_slot;
  if (s >= 32) return;

  const int c0   = s * 24;
  const int l    = tid & 63;
  const int wv   = tid >> 6;                // 0:(H,p0) 1:(H,p1) 2:(P,p0) 3:(P,p1)
  const int matP = wv >> 1;                 // 0=W_h, 1=W_p
  const int p    = wv & 1;                  // K-half
  const int colW = l & 31;
  const int khB  = l >> 5;
  const bool validC = (colW < 24);
  const int colB = validC ? colW : colW - 24;
  const int gran = colB*2 + khB;
  const int grr  = gran >> 3, gcc = gran & 7;
  const int bfi  = grr*8 + (gcc ^ (grr & 7));   // f16x8 index within a 384-u16 unit-block

  // per-(g,slot) monotonic flags: FL[s*32], 128B stride  [r15]
  u32* FL = ctr + 2048 + (size_t)gx*16384;

  // stage packed weight slice global -> LDS (153.6 KB)
  {
    const float4* srcw = reinterpret_cast<const float4*>(Wb + (size_t)s*76800);
    float4* dst = reinterpret_cast<float4*>(smem);
    for (int i = tid; i < 9600; i += 256) dst[i] = srcw[i];
  }
  __syncthreads();

  const f16x8* WBp = reinterpret_cast<const f16x8*>(smem);
  float* scr = reinterpret_cast<float*>(smem + 76800);   // 8KB: R0=scr[0..1023], R1=scr[1024..2047]
  const int mb = matP*100;                  // unit-block base for this wave's matrix

  const int dcol = c0 + (validC ? colW : 0);
  float bhv = 0.f, bpv = 0.f;
  if (wv < 2){ bhv = bh_g[dcol]; bpv = bp_g[dcol]; }

  float hz[16] = {}, hy[16] = {};           // fp32 master state (w0: m0, w1: m1)

  auto wait_flags = [&](u32 tgt){
    if (s_dead) return;
    long spins = 0;
    for (;;){
      bool ok = true;
      if (l < 32) ok = (__hip_atomic_load(FL + l*32, __ATOMIC_RELAXED, __HIP_MEMORY_SCOPE_AGENT) >= tgt);
      if (__all(ok)) break;
      __builtin_amdgcn_s_sleep(1);
      if (++spins > 1000000L){ if (l == 0) s_dead = 1; break; }
    }
  };

// state loop: NU units, global unit U0+i (B idx mb+U0+i), tile k'-offset
// U0-4+i, BOTH m-tiles, 8-deep dual A ring, squares for P-waves.
#define SLOOP(U0c, NUc, DOSQc) do { \
    f16x8 av0[8], av1[8]; \
    _Pragma("unroll") \
    for (int j = 0; j < 8; ++j){ \
      av0[j] = *reinterpret_cast<const f16x8*>(stb0 + (size_t)((U0c)-4+j)*16); \
      av1[j] = *reinterpret_cast<const f16x8*>(stb1 + (size_t)((U0c)-4+j)*16); \
    } \
    _Pragma("unroll") \
    for (int i = 0; i < (NUc); ++i){ \
      f16x8 b8 = WBp[(mb + (U0c) + i)*48 + bfi]; \
      f16x8 a0 = av0[i&7], a1 = av1[i&7]; \
      if (i + 8 < (NUc)){ \
        av0[i&7] = *reinterpret_cast<const f16x8*>(stb0 + (size_t)((U0c)+4+i)*16); \
        av1[i&7] = *reinterpret_cast<const f16x8*>(stb1 + (size_t)((U0c)+4+i)*16); \
      } \
      if (DOSQc){ a0 = a0*a0; a1 = a1*a1; } \
      acc0 = MFMA32(a0, b8, acc0); \
      acc1 = MFMA32(a1, b8, acc1); \
    } } while (0)

#pragma unroll 1
  for (int t = 0; t < T_STEPS; ++t){
    // x prefetch + convert (p0 waves; both m; mat-flavored) — pre-wait
    f16x8 xa0[4], xa1[4];
    if (p == 0){
#pragma unroll
      for (int mm = 0; mm < 2; ++mm){
        const float* xb = x + ((size_t)t*BATCH + gx*64 + mm*32 + colW)*64 + khB*8;
#pragma unroll
        for (int u = 0; u < 4; ++u){
          const float4 uu = *reinterpret_cast<const float4*>(xb + u*16);
          const float4 vv = *reinterpret_cast<const float4*>(xb + u*16 + 4);
          f16x8 r;
          if (!matP){
            r[0]=(_Float16)uu.x; r[1]=(_Float16)uu.y; r[2]=(_Float16)uu.z; r[3]=(_Float16)uu.w;
            r[4]=(_Float16)vv.x; r[5]=(_Float16)vv.y; r[6]=(_Float16)vv.z; r[7]=(_Float16)vv.w;
          } else {
            r[0]=(_Float16)(uu.x*uu.x); r[1]=(_Float16)(uu.y*uu.y); r[2]=(_Float16)(uu.z*uu.z); r[3]=(_Float16)(uu.w*uu.w);
            r[4]=(_Float16)(vv.x*vv.x); r[5]=(_Float16)(vv.y*vv.y); r[6]=(_Float16)(vv.z*vv.z); r[7]=(_Float16)(vv.w*vv.w);
          }
          if (mm) xa1[u] = r; else xa0[u] = r;
        }
      }
    }

    if (wv == 0){
      if (t > 0) wait_flags((u32)t);        // all slots finished step t-1
      ACQUIRE_L1();
    }
    __syncthreads();
    if (s_dead) break;

    const u16* stb0 = st + ((((size_t)(t&1)*8 + gx)*64) + colW)*1536 + khB*8;
    const u16* stb1 = stb0 + (size_t)32*1536;

    f32x16 acc0 = {}, acc1 = {};
    if (p == 0){
#pragma unroll
      for (int u = 0; u < 4; ++u){          // x units 0..3 (pre-flavored per mat)
        f16x8 b8 = WBp[(mb + u)*48 + bfi];
        acc0 = MFMA32(xa0[u], b8, acc0);
        acc1 = MFMA32(xa1[u], b8, acc1);
      }
      if (!matP) SLOOP(4, 46, 0); else SLOOP(4, 46, 1);
    } else {
      if (!matP) SLOOP(50, 50, 0); else SLOOP(50, 50, 1);
    }

    // 3-phase exchange through R0/R1 (e-major: e*64+l, conflict-free r14)
    float aH[16], aP[16];
    // Ph1 (H halves): w1 -> R0 (m0), w0 -> R1 (m1)
    if (wv == 1){
#pragma unroll
      for (int e = 0; e < 16; ++e) scr[e*64 + l] = acc0[e];
    } else if (wv == 0){
#pragma unroll
      for (int e = 0; e < 16; ++e) scr[1024 + e*64 + l] = acc1[e];
    }
    __syncthreads();
    if (wv == 0){
#pragma unroll
      for (int e = 0; e < 16; ++e) aH[e] = acc0[e] + scr[e*64 + l];
    } else if (wv == 1){
#pragma unroll
      for (int e = 0; e < 16; ++e) aH[e] = acc1[e] + scr[1024 + e*64 + l];
    }
    __syncthreads();
    // Ph2 (P first halves): w2 -> R0 (m0,p0), w3 -> R1 (m1,p1)
    if (wv == 2){
#pragma unroll
      for (int e = 0; e < 16; ++e) scr[e*64 + l] = acc0[e];
    } else if (wv == 3){
#pragma unroll
      for (int e = 0; e < 16; ++e) scr[1024 + e*64 + l] = acc1[e];
    }
    __syncthreads();
    if (wv == 0){
#pragma unroll
      for (int e = 0; e < 16; ++e) aP[e] = scr[e*64 + l];
    } else if (wv == 1){
#pragma unroll
      for (int e = 0; e < 16; ++e) aP[e] = scr[1024 + e*64 + l];
    }
    __syncthreads();
    // Ph3 (P second halves): w3 -> R0 (m0,p1), w2 -> R1 (m1,p0)
    if (wv == 3){
#pragma unroll
      for (int e = 0; e < 16; ++e) scr[e*64 + l] = acc0[e];
    } else if (wv == 2){
#pragma unroll
      for (int e = 0; e < 16; ++e) scr[1024 + e*64 + l] = acc1[e];
    }
    __syncthreads();

    if (wv < 2){
      u16* wtb = st + (((size_t)((t+1)&1)*8 + gx)*64)*1536;
      const int mrow = wv*32;
      const int rbase = wv ? 1024 : 0;
#pragma unroll
      for (int e = 0; e < 16; ++e){
        float aPf = aP[e] + scr[rbase + e*64 + l];
        float hv = ftanh(aH[e] + bhv);
        float pv = ftanh(aPf + bpv);
        hz[e] += DTF * (hv + pv);
        hy[e] += DTF * hz[e];
        if (validC){
          int row = mrow + (e & 3) + 8*(e >> 2) + 4*khB;
          wtb[(size_t)row*1536 + dcol]       = f2h(hz[e]);
          wtb[(size_t)row*1536 + 768 + dcol] = f2h(hy[e]);
        }
      }
      asm volatile("s_waitcnt vmcnt(0)" ::: "memory");   // updater stores in XCD L2
    }
    __syncthreads();
    if (tid == 0)
      __hip_atomic_store(FL + s*32, (u32)(t+1), __ATOMIC_RELAXED, __HIP_MEMORY_SCOPE_AGENT);
  }
#undef SLOOP

  // final projection: out = hy @ W_r^T + b_r, slot-0 block (16x16x32 path)
  if (s == 0 && !s_dead){
    if (wv == 0){ wait_flags((u32)T_STEPS); ACQUIRE_L1(); }
    __syncthreads();
    if (!s_dead){
      const int colL = l & 15, kq4 = l >> 4;
      const u16* hyb = st + (((size_t)gx*64) + wv*16 + colL)*1536 + 768 + kq4*8;  // buf0
      const f16x8* Wr8 = reinterpret_cast<const f16x8*>(Wrb);
      f32x4 oc[4] = {};
#pragma unroll
      for (int kt = 0; kt < 24; ++kt){
        f16x8 a = *reinterpret_cast<const f16x8*>(hyb + (size_t)kt*32);
#pragma unroll
        for (int nt = 0; nt < 4; ++nt)
          oc[nt] = MFMA16(a, Wr8[(nt*24 + kt)*64 + l], oc[nt]);
      }
      const int rowC = wv*16 + kq4*4;
#pragma unroll
      for (int nt = 0; nt < 4; ++nt){
        float bb = br_g[nt*16 + colL];
#pragma unroll
        for (int e = 0; e < 4; ++e)
          out[(size_t)(gx*64 + rowC + e)*64 + nt*16 + colL] = oc[nt][e] + bb;
      }
    }
  }
}

extern "C" void kernel_launch(void* const* d_in, const int* in_sizes, int n_in,
                              void* d_out, int out_size, void* d_ws, size_t ws_size,
                              hipStream_t stream) {
  const float* x  = (const float*)d_in[0];
  const float* Wh = (const float*)d_in[1];
  const float* bh = (const float*)d_in[2];
  const float* Wp = (const float*)d_in[3];
  const float* bp = (const float*)d_in[4];
  const float* Wr = (const float*)d_in[5];
  const float* br = (const float*)d_in[6];
  float* out = (float*)d_out;

  if (ws_size < (size_t)WS_NEED) return;    // loud failure: output stays zero
  char* ws = (char*)d_ws;

  u16* Wb  = (u16*)(ws + WB_OFF);
  u16* Wrb = (u16*)(ws + WRB_OFF);
  u16* st  = (u16*)(ws + ST_OFF);
  u32* ctr = (u32*)(ws + CTR_OFF);

  hipMemsetAsync(ws + CTR_OFF, 0, CTR_SZ, stream);   // slot counters + flags
  hipMemsetAsync(ws + ST_OFF,  0, ST_SZ,  stream);   // zero initial state (t=0)

  prep_weights<<<6496, 64, 0, stream>>>(Wh, Wp, Wr, Wb, Wrb);

  (void)hipFuncSetAttribute(reinterpret_cast<const void*>(rnn_main),
                            hipFuncAttributeMaxDynamicSharedMemorySize, 161792);
  rnn_main<<<256, 256, 161792, stream>>>(x, bh, bp, br, Wb, Wrb, st, ctr, out);
}

// Round 19
// 7261.556 us; speedup vs baseline: 1.2156x; 1.0697x over previous
//
#include <hip/hip_runtime.h>
#include <hip/hip_fp16.h>

typedef _Float16 f16x8 __attribute__((ext_vector_type(8)));
typedef float f32x4 __attribute__((ext_vector_type(4)));
typedef float f32x16 __attribute__((ext_vector_type(16)));
typedef unsigned short u16;
typedef unsigned int u32;

#define T_STEPS 512
#define BATCH   512
#define DTF     0.01f

// workspace layout (bytes)
#define CTR_OFF 0
#define CTR_SZ  1048576                     // slot counters + per-(g,slot) flags
#define WB_OFF  (CTR_OFF + CTR_SZ)
#define WB_SZ   (32*200*384*2)              // 4,915,200  [slice][mat*100+unit][384 u16] 32x32 B-frags
#define WRB_OFF (WB_OFF + WB_SZ)
#define WRB_SZ  (4*24*64*8*2)               // 98,304     W_r f16 B-frag layout (16x16x32)
#define ST_OFF  (WRB_OFF + WRB_SZ)
#define ST_SZ   (2*8*64*1536*2)             // 3,145,728  state [buf][g][row 64][k' 1536] f16
#define WS_NEED (ST_OFF + ST_SZ)

#define MFMA32(a,b,c) __builtin_amdgcn_mfma_f32_32x32x16_f16((a),(b),(c),0,0,0)
#define MFMA16(a,b,c) __builtin_amdgcn_mfma_f32_16x16x32_f16((a),(b),(c),0,0,0)

// Intra-XCD acquire: L2 is the coherence point, L1 write-through => L1-only
// invalidate; one wave per CU. [Verified rounds 3-18.]
#define ACQUIRE_L1() asm volatile("s_waitcnt vmcnt(0)\n\tbuffer_inv sc0" ::: "memory")

__device__ __forceinline__ u16 f2h(float f){ _Float16 h = (_Float16)f; return *reinterpret_cast<u16*>(&h); }
__device__ __forceinline__ float h2f(u16 u){ _Float16 h = *reinterpret_cast<_Float16*>(&u); return (float)h; }

__device__ __forceinline__ float ftanh(float x){
  float a = fminf(fmaxf(x, -12.f), 12.f);
  float e = __expf(2.f * a);
  return 1.f - 2.f * __builtin_amdgcn_rcpf(e + 1.f);
}

// ---- 32x32x16 fragment maps [verified r12/r14: absmax 0.03125] ----
// A (32x16): lane holds A[l&31][(l>>5)*8 + e]
// B (16x32): lane holds B[(l>>5)*8 + e][l&31]
// C (32x32): lane covers col = l&31, rows = (e&3) + 8*(e>>2) + 4*(l>>5)
// Wb layout unchanged (prep identical to r12-18).

__global__ __launch_bounds__(64) void prep_weights(const float* __restrict__ Wh,
                                                   const float* __restrict__ Wp,
                                                   const float* __restrict__ Wr,
                                                   u16* __restrict__ Wb, u16* __restrict__ Wrb){
  int b = blockIdx.x, l = threadIdx.x;
  if (b < 6400){
    int s = b / 200, r2 = b % 200;
    int m2 = r2 / 100, u = r2 % 100;
    if (l < 48){
      int c = l >> 1, kh = l & 1;
      int gg = c*2 + kh, rr = gg >> 3, cc = gg & 7;
      size_t dst = (size_t)s*76800 + (size_t)(m2*100 + u)*384 + (size_t)rr*64 + (size_t)((cc ^ (rr & 7))*8);
      const float* W = m2 ? Wp : Wh;
      const float* src = W + (size_t)(s*24 + c)*1600 + u*16 + kh*8;
      f16x8 o;
#pragma unroll
      for (int e = 0; e < 8; ++e) o[e] = (_Float16)src[e];
      *reinterpret_cast<f16x8*>(Wb + dst) = o;
    }
  } else {
    int b2 = b - 6400;                      // 0..95  (W_r, 16x16x32 B-frags)
    int nt = b2 / 24, kt = b2 % 24;
    int c = nt*16 + (l & 15), k = kt*32 + (l >> 4)*8;
    const float* src = Wr + (size_t)c*768 + k;
    f16x8 o;
#pragma unroll
    for (int e = 0; e < 8; ++e) o[e] = (_Float16)src[e];
    *reinterpret_cast<f16x8*>(Wrb + ((size_t)b2*64 + l)*8) = o;
  }
}

// grid = 256 x 256 (4 waves). Group = PHYSICAL XCD, slot via atomicAdd:
// 32 blocks/XCD. Slot s owns out-cols [s*24,+24) of BOTH W_h/W_p.
// Wave (m = w&1, p = w>>1): m-tile rows [m*32,+32), K-half p. 32x32x16 MFMA
// (r12) + e-major conflict-free scratch (r14) + per-slot flag sync (r15).
// THIS ROUND: single-phase exchange — partials stored as f16 so all 4
// regions (m0H,m0P,m1H,m1P) fit the 8KB scratch at once: 5 barriers/step -> 3,
// 2 cross-wave dependency round-trips -> 1. Compute path otherwise identical.
__global__ __launch_bounds__(256, 1) void rnn_main(
    const float* __restrict__ x, const float* __restrict__ bh_g, const float* __restrict__ bp_g,
    const float* __restrict__ br_g, const u16* __restrict__ Wb, const u16* __restrict__ Wrb,
    u16* __restrict__ st, u32* __restrict__ ctr, float* __restrict__ out)
{
  extern __shared__ u16 smem[];             // [0,153600): B-frags; [153600,161792): f16 scratch
  __shared__ int s_dead, s_slot, s_xcd;

  const int tid = threadIdx.x;
  if (tid == 0){
    s_dead = 0;
    u32 xcd;
    asm volatile("s_getreg_b32 %0, hwreg(HW_REG_XCC_ID)" : "=s"(xcd));
    xcd &= 7u;
    s_xcd  = (int)xcd;
    s_slot = (int)atomicAdd(ctr + xcd, 1u); // device-scope, ctr pre-zeroed
  }
  __syncthreads();
  const int gx = s_xcd;
  const int s  = s_slot;
  if (s >= 32) return;

  const int c0   = s * 24;
  const int l    = tid & 63;
  const int w    = tid >> 6;
  const int m    = w & 1;                   // m-tile (rows m*32..+32)
  const int p    = w >> 1;                  // K-half
  const int colW = l & 31;
  const int khB  = l >> 5;
  const bool validC = (colW < 24);
  const int colB = validC ? colW : colW - 24;
  const int gran = colB*2 + khB;
  const int grr  = gran >> 3, gcc = gran & 7;
  const int bfi  = grr*8 + (gcc ^ (grr & 7));   // f16x8 index within a 384-u16 unit-block

  // per-(g,slot) monotonic flags: FL[s*32], 128B stride  [r15]
  u32* FL = ctr + 2048 + (size_t)gx*16384;

  // stage packed weight slice global -> LDS (153.6 KB)
  {
    const float4* srcw = reinterpret_cast<const float4*>(Wb + (size_t)s*76800);
    float4* dst = reinterpret_cast<float4*>(smem);
    for (int i = tid; i < 9600; i += 256) dst[i] = srcw[i];
  }
  __syncthreads();

  const f16x8* WBp = reinterpret_cast<const f16x8*>(smem);
  u16* scr16 = smem + 76800;                // 8KB f16 scratch: region(m,which)=(m*2+which)*1024 + e*64 + l

  // x-unit B-frags (units 0..3, both mats) held permanently in registers (p==0)
  f16x8 xbh[4], xbp[4];
  if (p == 0){
#pragma unroll
    for (int u = 0; u < 4; ++u){ xbh[u] = WBp[u*48 + bfi]; xbp[u] = WBp[(100+u)*48 + bfi]; }
  }

  const int dcol = c0 + (validC ? colW : 0);
  float bhv = 0.f, bpv = 0.f;
  if (w < 2){ bhv = bh_g[dcol]; bpv = bp_g[dcol]; }

  float hz[16] = {}, hy[16] = {};           // fp32 master state (w0: m0, w1: m1)

  auto wait_flags = [&](u32 tgt){
    if (s_dead) return;
    long spins = 0;
    for (;;){
      bool ok = true;
      if (l < 32) ok = (__hip_atomic_load(FL + l*32, __ATOMIC_RELAXED, __HIP_MEMORY_SCOPE_AGENT) >= tgt);
      if (__all(ok)) break;
      __builtin_amdgcn_s_sleep(1);
      if (++spins > 1000000L){ if (l == 0) s_dead = 1; break; }
    }
  };

#define STATE_LOOP(U0c, NUc) do { \
    f16x8 av[4]; \
    _Pragma("unroll") \
    for (int i = 0; i < 4; ++i) av[i] = *reinterpret_cast<const f16x8*>(stb + (size_t)((U0c)-4+i)*16); \
    _Pragma("unroll") \
    for (int i = 0; i < (NUc); ++i){ \
      f16x8 a = av[i & 3]; \
      if (i + 4 < (NUc)) av[i & 3] = *reinterpret_cast<const f16x8*>(stb + (size_t)((U0c)+i)*16); \
      f16x8 bh8 = WBp[((U0c)+i)*48 + bfi]; \
      f16x8 bp8 = WBp[(100+(U0c)+i)*48 + bfi]; \
      f16x8 asq = a*a; \
      accH = MFMA32(a,   bh8, accH); \
      accP = MFMA32(asq, bp8, accP); \
    } } while (0)

#pragma unroll 1
  for (int t = 0; t < T_STEPS; ++t){
    f32x16 accH = {}, accP = {};

    // x contribution (units 0..3): independent of the tile — done pre-wait
    if (p == 0){
      const float* xb = x + ((size_t)t*BATCH + gx*64 + m*32 + colW)*64 + khB*8;
#pragma unroll
      for (int u = 0; u < 4; ++u){
        const float4 uu = *reinterpret_cast<const float4*>(xb + u*16);
        const float4 vv = *reinterpret_cast<const float4*>(xb + u*16 + 4);
        f16x8 xa8, xs8;
        xa8[0]=(_Float16)uu.x; xa8[1]=(_Float16)uu.y; xa8[2]=(_Float16)uu.z; xa8[3]=(_Float16)uu.w;
        xa8[4]=(_Float16)vv.x; xa8[5]=(_Float16)vv.y; xa8[6]=(_Float16)vv.z; xa8[7]=(_Float16)vv.w;
        xs8[0]=(_Float16)(uu.x*uu.x); xs8[1]=(_Float16)(uu.y*uu.y); xs8[2]=(_Float16)(uu.z*uu.z); xs8[3]=(_Float16)(uu.w*uu.w);
        xs8[4]=(_Float16)(vv.x*vv.x); xs8[5]=(_Float16)(vv.y*vv.y); xs8[6]=(_Float16)(vv.z*vv.z); xs8[7]=(_Float16)(vv.w*vv.w);
        accH = MFMA32(xa8, xbh[u], accH);
        accP = MFMA32(xs8, xbp[u], accP);
      }
    }

    if (w == 0){
      if (t > 0) wait_flags((u32)t);        // all slots finished step t-1
      ACQUIRE_L1();
    }
    __syncthreads();                        // barrier 1/3
    if (s_dead) break;

    // state A-frags: lane reads 16B at row = m*32+colW, k-offset khB*8 (plain layout)
    const u16* stb = st + ((((size_t)(t&1)*8 + gx)*64) + m*32 + colW)*1536 + khB*8;
    if (p == 0) STATE_LOOP(4, 46); else STATE_LOOP(50, 50);

    // SINGLE-PHASE exchange: p1 waves publish BOTH partials as f16 (4 regions
    // fit 8KB); e-major (lanes stride-1) — conflict-free per r14.
    if (p == 1){
#pragma unroll
      for (int e = 0; e < 16; ++e){
        scr16[(m*2+0)*1024 + e*64 + l] = f2h(accH[e]);
        scr16[(m*2+1)*1024 + e*64 + l] = f2h(accP[e]);
      }
    }
    __syncthreads();                        // barrier 2/3

    if (p == 0){
      u16* wtb = st + (((size_t)((t+1)&1)*8 + gx)*64)*1536;
#pragma unroll
      for (int e = 0; e < 16; ++e){
        float aH = accH[e] + h2f(scr16[(m*2+0)*1024 + e*64 + l]);
        float aP = accP[e] + h2f(scr16[(m*2+1)*1024 + e*64 + l]);
        float hv = ftanh(aH + bhv);
        float pv = ftanh(aP + bpv);
        hz[e] += DTF * (hv + pv);
        hy[e] += DTF * hz[e];
        if (validC){
          int row = m*32 + (e & 3) + 8*(e >> 2) + 4*khB;
          wtb[(size_t)row*1536 + dcol]       = f2h(hz[e]);
          wtb[(size_t)row*1536 + 768 + dcol] = f2h(hy[e]);
        }
      }
      asm volatile("s_waitcnt vmcnt(0)" ::: "memory");   // updater stores in XCD L2
    }
    __syncthreads();                        // barrier 3/3
    if (tid == 0)
      __hip_atomic_store(FL + s*32, (u32)(t+1), __ATOMIC_RELAXED, __HIP_MEMORY_SCOPE_AGENT);
  }
#undef STATE_LOOP

  // final projection: out = hy @ W_r^T + b_r, slot-0 block (16x16x32 path)
  if (s == 0 && !s_dead){
    if (w == 0){ wait_flags((u32)T_STEPS); ACQUIRE_L1(); }
    __syncthreads();
    if (!s_dead){
      const int colL = l & 15, kq4 = l >> 4;
      const u16* hyb = st + (((size_t)gx*64) + w*16 + colL)*1536 + 768 + kq4*8;  // buf0
      const f16x8* Wr8 = reinterpret_cast<const f16x8*>(Wrb);
      f32x4 oc[4] = {};
#pragma unroll
      for (int kt = 0; kt < 24; ++kt){
        f16x8 a = *reinterpret_cast<const f16x8*>(hyb + (size_t)kt*32);
#pragma unroll
        for (int nt = 0; nt < 4; ++nt)
          oc[nt] = MFMA16(a, Wr8[(nt*24 + kt)*64 + l], oc[nt]);
      }
      const int rowC = w*16 + kq4*4;
#pragma unroll
      for (int nt = 0; nt < 4; ++nt){
        float bb = br_g[nt*16 + colL];
#pragma unroll
        for (int e = 0; e < 4; ++e)
          out[(size_t)(gx*64 + rowC + e)*64 + nt*16 + colL] = oc[nt][e] + bb;
      }
    }
  }
}

extern "C" void kernel_launch(void* const* d_in, const int* in_sizes, int n_in,
                              void* d_out, int out_size, void* d_ws, size_t ws_size,
                              hipStream_t stream) {
  const float* x  = (const float*)d_in[0];
  const float* Wh = (const float*)d_in[1];
  const float* bh = (const float*)d_in[2];
  const float* Wp = (const float*)d_in[3];
  const float* bp = (const float*)d_in[4];
  const float* Wr = (const float*)d_in[5];
  const float* br = (const float*)d_in[6];
  float* out = (float*)d_out;

  if (ws_size < (size_t)WS_NEED) return;    // loud failure: output stays zero
  char* ws = (char*)d_ws;

  u16* Wb  = (u16*)(ws + WB_OFF);
  u16* Wrb = (u16*)(ws + WRB_OFF);
  u16* st  = (u16*)(ws + ST_OFF);
  u32* ctr = (u32*)(ws + CTR_OFF);

  hipMemsetAsync(ws + CTR_OFF, 0, CTR_SZ, stream);   // slot counters + flags
  hipMemsetAsync(ws + ST_OFF,  0, ST_SZ,  stream);   // zero initial state (t=0)

  prep_weights<<<6496, 64, 0, stream>>>(Wh, Wp, Wr, Wb, Wrb);

  (void)hipFuncSetAttribute(reinterpret_cast<const void*>(rnn_main),
                            hipFuncAttributeMaxDynamicSharedMemorySize, 161792);
  rnn_main<<<256, 256, 161792, stream>>>(x, bh, bp, br, Wb, Wrb, st, ctr, out);
}